// Round 1
// baseline (827.761 us; speedup 1.0000x reference)
//
#include <hip/hip_runtime.h>
#include <math.h>

#define Hdim    2048
#define HALF_H  1024
#define Bsz     4
#define Sdim    4096
#define Mrows   (Bsz * Sdim)        // 16384 rows per tensor
#define NROWS   (2 * Mrows)         // 32768 total row-tasks

// ws layout (floats):
//   [0,      8192)  : colsum  (B*H)        -- zeroed via hipMemsetAsync
//   [8192,  12288)  : hpart   (B*H/2)      -- zeroed via hipMemsetAsync
//   [12288]         : rank_idx (as int)    -- written by mlp2_kernel

// ---------------- K1: column sums of keys over S, per batch ----------------
// grid (4, 2, 128), block 256. Each block: 32 rows x 1024 cols (float4/thread).
__global__ void colsum_kernel(const float* __restrict__ keys,
                              float* __restrict__ sums) {
    const int b  = blockIdx.x;        // batch
    const int cc = blockIdx.y;        // column half
    const int rb = blockIdx.z;        // row chunk (32 rows)
    const int col = cc * 1024 + threadIdx.x * 4;
    const float* base = keys + ((size_t)(b * Sdim + rb * 32)) * Hdim + col;
    float4 acc = make_float4(0.f, 0.f, 0.f, 0.f);
    #pragma unroll 4
    for (int r = 0; r < 32; ++r) {
        const float4 v = *(const float4*)(base + (size_t)r * Hdim);
        acc.x += v.x; acc.y += v.y; acc.z += v.z; acc.w += v.w;
    }
    float* s = sums + b * Hdim + col;
    atomicAdd(s + 0, acc.x);
    atomicAdd(s + 1, acc.y);
    atomicAdd(s + 2, acc.z);
    atomicAdd(s + 3, acc.w);
}

// ---------------- K2: hpart[b][j] += sum_{i in kb} mean[b][i]*w1[i][j] -----
// grid (4, 4, 8), block 256.
__global__ void mlp1_kernel(const float* __restrict__ sums,
                            const float* __restrict__ w1,
                            float* __restrict__ hpart) {
    const int b  = blockIdx.x;
    const int jb = blockIdx.y;
    const int kb = blockIdx.z;
    const int j  = jb * 256 + threadIdx.x;
    const float inv = 1.0f / (float)Sdim;
    float acc = 0.f;
    const int i0 = kb * 256;
    #pragma unroll 4
    for (int i = i0; i < i0 + 256; ++i) {
        acc = fmaf(sums[b * Hdim + i] * inv, w1[(size_t)i * HALF_H + j], acc);
    }
    atomicAdd(&hpart[b * HALF_H + j], acc);
}

// ---------------- K3: relu, @w2, sigmoid, avg, threshold -> rank_idx ------
// 1 block, 1024 threads.
__global__ void mlp2_kernel(const float* __restrict__ hpart,
                            const float* __restrict__ b1,
                            const float* __restrict__ w2,
                            const float* __restrict__ b2,
                            int* __restrict__ rank_sel) {
    const int j = threadIdx.x;           // 0..1023
    __shared__ float wpart[16];
    __shared__ float avg_sh;
    if (j == 0) avg_sh = 0.f;
    __syncthreads();
    for (int b = 0; b < Bsz; ++b) {
        float hv = hpart[b * HALF_H + j] + b1[j];
        hv = fmaxf(hv, 0.f);
        float v = hv * w2[j];
        #pragma unroll
        for (int off = 32; off > 0; off >>= 1) v += __shfl_down(v, off, 64);
        const int wave = j >> 6, lane = j & 63;
        if (lane == 0) wpart[wave] = v;
        __syncthreads();
        if (j == 0) {
            float s = 0.f;
            #pragma unroll
            for (int w = 0; w < 16; ++w) s += wpart[w];
            s += b2[0];
            avg_sh += 1.0f / (1.0f + expf(-s));
        }
        __syncthreads();
    }
    if (j == 0) {
        const float avg = avg_sh * 0.25f;
        *rank_sel = (avg >= 0.3f ? 1 : 0) + (avg >= 0.7f ? 1 : 0);
    }
}

// ---------------- K4: out_row = x_row + (x_row @ A) @ B -------------------
template <int R>
__device__ __forceinline__ void row_lora(const float* __restrict__ srow,
                                         float* __restrict__ drow,
                                         const float* __restrict__ A,
                                         const float* __restrict__ Bm,
                                         float (*pw)[16], float* pf) {
    const int tid = threadIdx.x;
    const int ibase = tid * 8;
    const float4 x0 = *(const float4*)(srow + ibase);
    const float4 x1 = *(const float4*)(srow + ibase + 4);
    const float x[8] = {x0.x, x0.y, x0.z, x0.w, x1.x, x1.y, x1.z, x1.w};

    float pl[R];
    #pragma unroll
    for (int j = 0; j < R; ++j) pl[j] = 0.f;
    #pragma unroll
    for (int u = 0; u < 8; ++u) {
        const float* arow = A + (size_t)(ibase + u) * R;
        #pragma unroll
        for (int j = 0; j < R; ++j) pl[j] = fmaf(x[u], arow[j], pl[j]);
    }
    // reduce across the block (4 waves of 64)
    #pragma unroll
    for (int j = 0; j < R; ++j) {
        #pragma unroll
        for (int off = 32; off > 0; off >>= 1)
            pl[j] += __shfl_down(pl[j], off, 64);
    }
    const int wave = tid >> 6, lane = tid & 63;
    if (lane == 0) {
        #pragma unroll
        for (int j = 0; j < R; ++j) pw[wave][j] = pl[j];
    }
    __syncthreads();
    if (tid < R) pf[tid] = (pw[0][tid] + pw[1][tid]) + (pw[2][tid] + pw[3][tid]);
    __syncthreads();

    float4 o0 = x0, o1 = x1;
    #pragma unroll
    for (int j = 0; j < R; ++j) {
        const float p = pf[j];
        const float4 b0 = *(const float4*)(Bm + (size_t)j * Hdim + ibase);
        const float4 b1v = *(const float4*)(Bm + (size_t)j * Hdim + ibase + 4);
        o0.x = fmaf(p, b0.x, o0.x);  o0.y = fmaf(p, b0.y, o0.y);
        o0.z = fmaf(p, b0.z, o0.z);  o0.w = fmaf(p, b0.w, o0.w);
        o1.x = fmaf(p, b1v.x, o1.x); o1.y = fmaf(p, b1v.y, o1.y);
        o1.z = fmaf(p, b1v.z, o1.z); o1.w = fmaf(p, b1v.w, o1.w);
    }
    *(float4*)(drow + ibase) = o0;
    *(float4*)(drow + ibase + 4) = o1;
}

__global__ void __launch_bounds__(256)
lora_apply_kernel(const float* __restrict__ keys, const float* __restrict__ values,
                  const float* kA0, const float* kB0, const float* vA0, const float* vB0,
                  const float* kA1, const float* kB1, const float* vA1, const float* vB1,
                  const float* kA2, const float* kB2, const float* vA2, const float* vB2,
                  const int* __restrict__ rank_sel, float* __restrict__ out) {
    __shared__ float pw[4][16];
    __shared__ float pf[16];
    const int row = blockIdx.x;           // 0..NROWS-1 : ck rows then cv rows
    const int idx = *rank_sel;            // block-uniform
    const bool isK = row < Mrows;
    const int m = isK ? row : row - Mrows;
    const float* src = isK ? keys : values;
    const float* A;
    const float* Bm;
    if (idx == 0)      { A = isK ? kA0 : vA0; Bm = isK ? kB0 : vB0; }
    else if (idx == 1) { A = isK ? kA1 : vA1; Bm = isK ? kB1 : vB1; }
    else               { A = isK ? kA2 : vA2; Bm = isK ? kB2 : vB2; }

    const float* srow = src + (size_t)m * Hdim;
    float* drow = out + (size_t)row * Hdim;
    if (idx == 0)      row_lora<4>(srow, drow, A, Bm, pw, pf);
    else if (idx == 1) row_lora<8>(srow, drow, A, Bm, pw, pf);
    else               row_lora<16>(srow, drow, A, Bm, pw, pf);
}

extern "C" void kernel_launch(void* const* d_in, const int* in_sizes, int n_in,
                              void* d_out, int out_size, void* d_ws, size_t ws_size,
                              hipStream_t stream) {
    const float* keys   = (const float*)d_in[0];
    const float* values = (const float*)d_in[1];
    const float* w1     = (const float*)d_in[2];
    const float* b1     = (const float*)d_in[3];
    const float* w2     = (const float*)d_in[4];
    const float* b2     = (const float*)d_in[5];
    const float* kA0 = (const float*)d_in[6];
    const float* kB0 = (const float*)d_in[7];
    const float* vA0 = (const float*)d_in[8];
    const float* vB0 = (const float*)d_in[9];
    const float* kA1 = (const float*)d_in[10];
    const float* kB1 = (const float*)d_in[11];
    const float* vA1 = (const float*)d_in[12];
    const float* vB1 = (const float*)d_in[13];
    const float* kA2 = (const float*)d_in[14];
    const float* kB2 = (const float*)d_in[15];
    const float* vA2 = (const float*)d_in[16];
    const float* vB2 = (const float*)d_in[17];

    float* ws_f   = (float*)d_ws;
    float* sums   = ws_f;                    // 8192 floats
    float* hpart  = ws_f + 8192;             // 4096 floats
    int*   ranksel = (int*)(ws_f + 12288);   // 1 int

    // zero accumulators (sums + hpart)
    hipMemsetAsync(d_ws, 0, (8192 + 4096) * sizeof(float), stream);

    colsum_kernel<<<dim3(Bsz, 2, 128), 256, 0, stream>>>(keys, sums);
    mlp1_kernel<<<dim3(Bsz, 4, 8), 256, 0, stream>>>(sums, w1, hpart);
    mlp2_kernel<<<1, 1024, 0, stream>>>(hpart, b1, w2, b2, ranksel);
    lora_apply_kernel<<<NROWS, 256, 0, stream>>>(
        keys, values,
        kA0, kB0, vA0, vB0,
        kA1, kB1, vA1, vB1,
        kA2, kB2, vA2, vB2,
        ranksel, (float*)d_out);
}

// Round 2
// 660.454 us; speedup vs baseline: 1.2533x; 1.2533x over previous
//
#include <hip/hip_runtime.h>
#include <math.h>

#define Hdim    2048
#define HALF_H  1024
#define Bsz     4
#define Sdim    4096
#define Mrows   (Bsz * Sdim)        // 16384 rows per tensor
#define NROWS   (2 * Mrows)         // 32768 total rows

// ws float layout:
//   [0,      131072) : cs_part  (16 chunks x 8192)   -- fully written, no memset
//   [131072, 139264) : mean     (4 x 2048)
//   [139264, 143360) : hpart    (4 x 1024)           -- memset to 0
//   [143360]         : rank_sel (int)
#define CS_PART_OFF 0
#define MEAN_OFF    131072
#define HPART_OFF   139264
#define RANK_OFF    143360

// ---------------- K1: partial column sums of keys (no atomics) -------------
// grid (4, 2, 16), block 256. Block: 256 rows x 1024 cols (float4/thread).
__global__ void __launch_bounds__(256)
colsum_part_kernel(const float* __restrict__ keys, float* __restrict__ cs_part) {
    const int b  = blockIdx.x;        // batch
    const int cc = blockIdx.y;        // column half
    const int rb = blockIdx.z;        // row chunk (256 rows)
    const int col = cc * 1024 + threadIdx.x * 4;
    const float* base = keys + ((size_t)(b * Sdim + rb * 256)) * Hdim + col;
    float4 acc = make_float4(0.f, 0.f, 0.f, 0.f);
    #pragma unroll 8
    for (int r = 0; r < 256; ++r) {
        const float4 v = *(const float4*)(base + (size_t)r * Hdim);
        acc.x += v.x; acc.y += v.y; acc.z += v.z; acc.w += v.w;
    }
    *(float4*)(cs_part + rb * 8192 + b * Hdim + col) = acc;
}

// ---------------- K2: reduce partials -> mean ------------------------------
// grid 32, block 256.
__global__ void cs_reduce_kernel(const float* __restrict__ cs_part,
                                 float* __restrict__ mean) {
    const int i = blockIdx.x * 256 + threadIdx.x;   // 0..8191
    float s = 0.f;
    #pragma unroll
    for (int k = 0; k < 16; ++k) s += cs_part[k * 8192 + i];
    mean[i] = s * (1.0f / (float)Sdim);
}

// ---------------- K3: hpart[b][j] += sum_i mean[b][i]*w1[i][j] -------------
// grid (4, 4, 8), block 256.
__global__ void mlp1_kernel(const float* __restrict__ mean,
                            const float* __restrict__ w1,
                            float* __restrict__ hpart) {
    const int b  = blockIdx.x;
    const int jb = blockIdx.y;
    const int kb = blockIdx.z;
    const int j  = jb * 256 + threadIdx.x;
    float acc = 0.f;
    const int i0 = kb * 256;
    #pragma unroll 8
    for (int i = i0; i < i0 + 256; ++i) {
        acc = fmaf(mean[b * Hdim + i], w1[(size_t)i * HALF_H + j], acc);
    }
    atomicAdd(&hpart[b * HALF_H + j], acc);
}

// ---------------- K4: relu, @w2, sigmoid, avg, threshold -> rank_idx ------
__global__ void mlp2_kernel(const float* __restrict__ hpart,
                            const float* __restrict__ b1,
                            const float* __restrict__ w2,
                            const float* __restrict__ b2,
                            int* __restrict__ rank_sel) {
    const int j = threadIdx.x;           // 0..1023
    __shared__ float wpart[16];
    __shared__ float avg_sh;
    if (j == 0) avg_sh = 0.f;
    __syncthreads();
    for (int b = 0; b < Bsz; ++b) {
        float hv = hpart[b * HALF_H + j] + b1[j];
        hv = fmaxf(hv, 0.f);
        float v = hv * w2[j];
        #pragma unroll
        for (int off = 32; off > 0; off >>= 1) v += __shfl_down(v, off, 64);
        const int wave = j >> 6, lane = j & 63;
        if (lane == 0) wpart[wave] = v;
        __syncthreads();
        if (j == 0) {
            float s = 0.f;
            #pragma unroll
            for (int w = 0; w < 16; ++w) s += wpart[w];
            s += b2[0];
            avg_sh += 1.0f / (1.0f + expf(-s));
        }
        __syncthreads();
    }
    if (j == 0) {
        const float avg = avg_sh * 0.25f;
        *rank_sel = (avg >= 0.3f ? 1 : 0) + (avg >= 0.7f ? 1 : 0);
    }
}

// ---------------- K5: P = X @ A, lane=row, waves split K -------------------
template <int R>
__device__ __forceinline__ void p_compute(const float* __restrict__ X,
                                          const float* __restrict__ A,
                                          float* __restrict__ P, int bk,
                                          float (*pp)[64][16]) {
    const int tid  = threadIdx.x;
    const int wave = tid >> 6, lane = tid & 63;
    const int m     = (bk & 255) * 64 + lane;   // row within tensor
    const int cbase = wave * 512;               // this wave's K range
    const float4* xp = (const float4*)(X + (size_t)m * Hdim + cbase);

    float acc[R];
    #pragma unroll
    for (int j = 0; j < R; ++j) acc[j] = 0.f;

    #pragma unroll 4
    for (int c4 = 0; c4 < 128; ++c4) {
        const float4 x = xp[c4];
        // wave-uniform A row base -> scalar loads
        const int c0 = __builtin_amdgcn_readfirstlane(cbase + c4 * 4);
        const float* ar = A + (size_t)c0 * R;
        const float xs[4] = {x.x, x.y, x.z, x.w};
        #pragma unroll
        for (int u = 0; u < 4; ++u) {
            #pragma unroll
            for (int j = 0; j < R; ++j)
                acc[j] = fmaf(xs[u], ar[u * R + j], acc[j]);
        }
    }

    #pragma unroll
    for (int j = 0; j < R; ++j) pp[wave][lane][j] = acc[j];
    __syncthreads();
    if (tid < 64) {
        const size_t r = (size_t)bk * 64 + tid;   // global out row
        float* pr = P + r * Hdim;                 // stash P in out row head
        #pragma unroll
        for (int j = 0; j < R; ++j)
            pr[j] = (pp[0][tid][j] + pp[1][tid][j]) +
                    (pp[2][tid][j] + pp[3][tid][j]);
    }
}

__global__ void __launch_bounds__(256)
p_pass_kernel(const float* __restrict__ keys, const float* __restrict__ values,
              const float* kA0, const float* kA1, const float* kA2,
              const float* vA0, const float* vA1, const float* vA2,
              const int* __restrict__ rank_sel, float* __restrict__ P) {
    __shared__ float pp[4][64][16];
    const int bk  = blockIdx.x;                 // 0..511; <256 keys, else values
    const int idx = *rank_sel;
    const bool isK = bk < 256;
    const float* X = isK ? keys : values;
    if (idx == 0)      p_compute<4>(X, isK ? kA0 : vA0, P, bk, pp);
    else if (idx == 1) p_compute<8>(X, isK ? kA1 : vA1, P, bk, pp);
    else               p_compute<16>(X, isK ? kA2 : vA2, P, bk, pp);
}

// ---------------- K6: out = x + P @ B, pure stream -------------------------
template <int R>
__device__ __forceinline__ void apply_row(const float* __restrict__ xrow,
                                          const float* __restrict__ prow,
                                          const float* __restrict__ B,
                                          float* __restrict__ orow) {
    const int t = threadIdx.x;
    float pj[R];
    #pragma unroll
    for (int j = 0; j < R; ++j) pj[j] = prow[j];
    __syncthreads();   // all P reads complete before any out write (P aliases orow)
    #pragma unroll
    for (int h = 0; h < 2; ++h) {
        const int c = (t + h * 256) * 4;
        float4 o = *(const float4*)(xrow + c);
        #pragma unroll
        for (int j = 0; j < R; ++j) {
            const float4 bv = *(const float4*)(B + (size_t)j * Hdim + c);
            o.x = fmaf(pj[j], bv.x, o.x);
            o.y = fmaf(pj[j], bv.y, o.y);
            o.z = fmaf(pj[j], bv.z, o.z);
            o.w = fmaf(pj[j], bv.w, o.w);
        }
        *(float4*)(orow + c) = o;
    }
}

__global__ void __launch_bounds__(256)
apply_kernel(const float* __restrict__ keys, const float* __restrict__ values,
             const float* kB0, const float* kB1, const float* kB2,
             const float* vB0, const float* vB1, const float* vB2,
             const int* __restrict__ rank_sel, float* __restrict__ out) {
    const int row = blockIdx.x;                 // 0..32767
    const int idx = *rank_sel;
    const bool isK = row < Mrows;
    const int m = row & (Mrows - 1);
    const float* xrow = (isK ? keys : values) + (size_t)m * Hdim;
    const float* prow = out + (size_t)row * Hdim;
    float* orow = out + (size_t)row * Hdim;
    const float* B = (idx == 0) ? (isK ? kB0 : vB0)
                   : (idx == 1) ? (isK ? kB1 : vB1)
                                : (isK ? kB2 : vB2);
    if (idx == 0)      apply_row<4>(xrow, prow, B, orow);
    else if (idx == 1) apply_row<8>(xrow, prow, B, orow);
    else               apply_row<16>(xrow, prow, B, orow);
}

extern "C" void kernel_launch(void* const* d_in, const int* in_sizes, int n_in,
                              void* d_out, int out_size, void* d_ws, size_t ws_size,
                              hipStream_t stream) {
    const float* keys   = (const float*)d_in[0];
    const float* values = (const float*)d_in[1];
    const float* w1     = (const float*)d_in[2];
    const float* b1     = (const float*)d_in[3];
    const float* w2     = (const float*)d_in[4];
    const float* b2     = (const float*)d_in[5];
    const float* kA0 = (const float*)d_in[6];
    const float* kB0 = (const float*)d_in[7];
    const float* vA0 = (const float*)d_in[8];
    const float* vB0 = (const float*)d_in[9];
    const float* kA1 = (const float*)d_in[10];
    const float* kB1 = (const float*)d_in[11];
    const float* vA1 = (const float*)d_in[12];
    const float* vB1 = (const float*)d_in[13];
    const float* kA2 = (const float*)d_in[14];
    const float* kB2 = (const float*)d_in[15];
    const float* vA2 = (const float*)d_in[16];
    const float* vB2 = (const float*)d_in[17];

    float* ws_f    = (float*)d_ws;
    float* cs_part = ws_f + CS_PART_OFF;
    float* mean    = ws_f + MEAN_OFF;
    float* hpart   = ws_f + HPART_OFF;
    int*   ranksel = (int*)(ws_f + RANK_OFF);
    float* out     = (float*)d_out;

    // zero only hpart (atomic accumulator)
    hipMemsetAsync(hpart, 0, HALF_H * Bsz * sizeof(float), stream);

    colsum_part_kernel<<<dim3(Bsz, 2, 16), 256, 0, stream>>>(keys, cs_part);
    cs_reduce_kernel<<<32, 256, 0, stream>>>(cs_part, mean);
    mlp1_kernel<<<dim3(Bsz, 4, 8), 256, 0, stream>>>(mean, w1, hpart);
    mlp2_kernel<<<1, 1024, 0, stream>>>(hpart, b1, w2, b2, ranksel);
    p_pass_kernel<<<512, 256, 0, stream>>>(keys, values,
                                           kA0, kA1, kA2, vA0, vA1, vA2,
                                           ranksel, out);
    apply_kernel<<<NROWS, 256, 0, stream>>>(keys, values,
                                            kB0, kB1, kB2, vB0, vB1, vB2,
                                            ranksel, out);
}